// Round 1
// baseline (124.151 us; speedup 1.0000x reference)
//
#include <hip/hip_runtime.h>
#include <hip/hip_bf16.h>

#define NN 8192
#define KK 256
#define HN 4096
#define BM 128
#define BNq 128
#define BK 64

typedef __attribute__((ext_vector_type(8))) short bf16x8;
typedef __attribute__((ext_vector_type(4))) float f32x4;

__device__ __forceinline__ void gload_lds16(const void* g, void* l) {
  __builtin_amdgcn_global_load_lds(
      (const __attribute__((address_space(1))) unsigned int*)g,
      (__attribute__((address_space(3))) unsigned int*)l, 16, 0, 0);
}

// ---- Kernel 1: row-normalize z (f32) -> zn (bf16), 1 wave per row ----
__global__ void nrm_kernel(const float* __restrict__ z,
                           unsigned short* __restrict__ zn) {
  int row = (blockIdx.x << 2) + (threadIdx.x >> 6);
  int lane = threadIdx.x & 63;
  float4 v = ((const float4*)(z + (size_t)row * KK))[lane];
  float ss = v.x * v.x + v.y * v.y + v.z * v.z + v.w * v.w;
#pragma unroll
  for (int off = 32; off; off >>= 1) ss += __shfl_xor(ss, off, 64);
  float scale = 1.0f / fmaxf(sqrtf(ss), 1e-8f);
  union {
    __hip_bfloat16 h[4];
    ushort4 u;
  } cv;
  cv.h[0] = __float2bfloat16(v.x * scale);
  cv.h[1] = __float2bfloat16(v.y * scale);
  cv.h[2] = __float2bfloat16(v.z * scale);
  cv.h[3] = __float2bfloat16(v.w * scale);
  ((ushort4*)zn)[(size_t)row * 64 + lane] = cv.u;
}

// ---- Kernel 2: fused Gram-GEMM + exp + row-sum + positive extraction ----
// S = Zn * Zn^T (cosine), logits = 10*S. rowsum[i] += sum_j exp(10*S-10),
// diagonal excluded; pos[i] = 10*S[i, i^4096].
__global__ __launch_bounds__(256) void gemm_kernel(
    const unsigned short* __restrict__ zn, float* __restrict__ rowsum,
    float* __restrict__ pos) {
  __shared__ short As[BM * BK];  // XOR-swizzled: 16B-group g stored at g^(row&7)
  __shared__ short Bs[BNq * BK];

  const int t = threadIdx.x;
  const int bm = blockIdx.x >> 6;
  const int bn = blockIdx.x & 63;
  const int l = t & 63;
  const int w = t >> 6;
  const int wr = w >> 1, wc = w & 1;

  f32x4 acc[4][4];
  const f32x4 vzero = {0.f, 0.f, 0.f, 0.f};
#pragma unroll
  for (int mi = 0; mi < 4; ++mi)
#pragma unroll
    for (int ni = 0; ni < 4; ++ni) acc[mi][ni] = vzero;

  const char* zb = (const char*)zn;
  const int rloc = t >> 3;                       // 0..31 (row within round)
  const int gsrc = (t & 7) ^ (rloc & 7);         // pre-swizzled global 16B-group

#pragma unroll
  for (int kt = 0; kt < KK / BK; ++kt) {
    __syncthreads();  // previous tile fully consumed
#pragma unroll
    for (int ro = 0; ro < 4; ++ro) {
      int r = ro * 32 + rloc;  // r&7 == rloc&7
      gload_lds16(zb + (size_t)(bm * BM + r) * 512 + kt * 128 + gsrc * 16,
                  (char*)As + ro * 4096 + t * 16);
      gload_lds16(zb + (size_t)(bn * BNq + r) * 512 + kt * 128 + gsrc * 16,
                  (char*)Bs + ro * 4096 + t * 16);
    }
    asm volatile("s_waitcnt vmcnt(0)" ::: "memory");
    __syncthreads();

#pragma unroll
    for (int kk = 0; kk < 2; ++kk) {
      bf16x8 af[4], bfr[4];
      int g = kk * 4 + (l >> 4);
#pragma unroll
      for (int mi = 0; mi < 4; ++mi) {
        int r = wr * 64 + mi * 16 + (l & 15);
        af[mi] = *(const bf16x8*)(As + r * 64 + ((g ^ (r & 7)) << 3));
      }
#pragma unroll
      for (int ni = 0; ni < 4; ++ni) {
        int r = wc * 64 + ni * 16 + (l & 15);
        bfr[ni] = *(const bf16x8*)(Bs + r * 64 + ((g ^ (r & 7)) << 3));
      }
#pragma unroll
      for (int mi = 0; mi < 4; ++mi)
#pragma unroll
        for (int ni = 0; ni < 4; ++ni)
          acc[mi][ni] = __builtin_amdgcn_mfma_f32_16x16x32_bf16(
              af[mi], bfr[ni], acc[mi][ni], 0, 0, 0);
    }
  }

  // ---- epilogue: exp(10*s - 10), mask diagonal, grab positive, row-sum ----
  const int rowBase = bm * BM + wr * 64 + ((l >> 4) << 2);
  const int colBase = bn * BNq + wc * 64 + (l & 15);
  const float C1 = 14.4269504088896340736f;  // 10*log2(e)
  float rs[4][4];
#pragma unroll
  for (int mi = 0; mi < 4; ++mi) {
#pragma unroll
    for (int j = 0; j < 4; ++j) rs[mi][j] = 0.f;
#pragma unroll
    for (int ni = 0; ni < 4; ++ni) {
#pragma unroll
      for (int j = 0; j < 4; ++j) {
        int gr = rowBase + mi * 16 + j;
        int gc = colBase + ni * 16;
        float a = acc[mi][ni][j];
        if (gc == (gr ^ HN)) pos[gr] = a * 10.0f;
        float p = (gc == gr) ? 0.0f : exp2f(fmaf(a, C1, -C1));
        rs[mi][j] += p;
      }
    }
  }
#pragma unroll
  for (int mi = 0; mi < 4; ++mi)
#pragma unroll
    for (int j = 0; j < 4; ++j) {
      float v = rs[mi][j];
#pragma unroll
      for (int off = 1; off < 16; off <<= 1) v += __shfl_xor(v, off, 64);
      if ((l & 15) == 0)
        atomicAdd(&rowsum[rowBase + mi * 16 + j], v);
    }
}

// ---- Kernel 3: loss = mean(10 + ln(rowsum_i) - pos_i) ----
__global__ void finalize_kernel(const float* __restrict__ rowsum,
                                const float* __restrict__ pos,
                                float* __restrict__ out) {
  int t = threadIdx.x;
  float acc = 0.f;
  for (int i = t; i < NN; i += 256)
    acc += 10.0f + logf(rowsum[i]) - pos[i];
#pragma unroll
  for (int off = 32; off; off >>= 1) acc += __shfl_xor(acc, off, 64);
  __shared__ float ws[4];
  if ((t & 63) == 0) ws[t >> 6] = acc;
  __syncthreads();
  if (t == 0) out[0] = (ws[0] + ws[1] + ws[2] + ws[3]) * (1.0f / (float)NN);
}

extern "C" void kernel_launch(void* const* d_in, const int* in_sizes, int n_in,
                              void* d_out, int out_size, void* d_ws,
                              size_t ws_size, hipStream_t stream) {
  const float* z = (const float*)d_in[0];
  float* out = (float*)d_out;
  unsigned short* zn = (unsigned short*)d_ws;                  // 4 MiB bf16
  float* rowsum = (float*)((char*)d_ws + (size_t)NN * KK * 2); // 32 KiB
  float* pos = rowsum + NN;                                    // 32 KiB

  nrm_kernel<<<NN / 4, 256, 0, stream>>>(z, zn);
  hipMemsetAsync(rowsum, 0, NN * sizeof(float), stream);
  gemm_kernel<<<(NN / BM) * (NN / BNq), 256, 0, stream>>>(zn, rowsum, pos);
  finalize_kernel<<<1, 256, 0, stream>>>(rowsum, pos, out);
}